// Round 13
// baseline (528.972 us; speedup 1.0000x reference)
//
#include <hip/hip_runtime.h>

constexpr int kB  = 512;
constexpr int kV  = 6890;
constexpr int kJ  = 24;
constexpr int kD  = kV * 3;   // 20670
constexpr int kNB = 10;
constexpr int kNF = 93;

// DIAGNOSTIC ROUND (r13): k14 body repeated x3, k5 body repeated x5.
// Idempotent (identical stores each rep); memory clobber prevents rep CSE.
// Purpose: k14/k5 have never been directly measured in this loop — inflate
// them above the ~75us harness fills so the top-5 table yields duration +
// counters. Solve {k14, k5} from top-5 + dur_us delta; revert next round.
#define K14_REPS 3
#define K5_REPS 5

// ---------------------------------------------------------------------------
// KA v3 (r12 form): v-split x4, partial slices, no atomics. grid(72,4).
// ---------------------------------------------------------------------------
__global__ __launch_bounds__(256) void kA_js(
    const float* __restrict__ Jreg, const float* __restrict__ shapedirs,
    const float* __restrict__ v_template, float* __restrict__ jsp,
    float* __restrict__ jtp) {
  int jk = blockIdx.x;
  int j = jk / 3, k = jk % 3;
  int tid = threadIdx.x;
  float acc[kNB];
  float accT = 0.f;
#pragma unroll
  for (int nb = 0; nb < kNB; ++nb) acc[nb] = 0.f;
  for (int v = blockIdx.y * 256 + tid; v < kV; v += 1024) {
    float w = Jreg[(size_t)j * kV + v];
    const float* srow = shapedirs + (size_t)(v * 3 + k) * kNB;
    accT += w * v_template[v * 3 + k];
#pragma unroll
    for (int nb = 0; nb < kNB; ++nb) acc[nb] += w * srow[nb];
  }
#pragma unroll
  for (int nb = 0; nb < kNB; ++nb)
#pragma unroll
    for (int off = 32; off > 0; off >>= 1)
      acc[nb] += __shfl_down(acc[nb], off, 64);
#pragma unroll
  for (int off = 32; off > 0; off >>= 1) accT += __shfl_down(accT, off, 64);
  __shared__ float red[4][11];
  int wave = tid >> 6, lane = tid & 63;
  if (lane == 0) {
#pragma unroll
    for (int nb = 0; nb < kNB; ++nb) red[wave][nb] = acc[nb];
    red[wave][10] = accT;
  }
  __syncthreads();
  if (tid == 0) {
#pragma unroll
    for (int nb = 0; nb < kNB; ++nb)
      jsp[(size_t)blockIdx.y * 720 + jk * kNB + nb] =
          red[0][nb] + red[1][nb] + red[2][nb] + red[3][nb];
    jtp[(size_t)blockIdx.y * 72 + jk] =
        red[0][10] + red[1][10] + red[2][10] + red[3][10];
  }
}

// ---------------------------------------------------------------------------
// KC v2 (r12 form): 4 batches per block, sums kA partials inline.
// ---------------------------------------------------------------------------
__global__ __launch_bounds__(256) void kC_batch(
    const float* __restrict__ pose, const float* __restrict__ betas,
    const float* __restrict__ trans, const float* __restrict__ jsp,
    const float* __restrict__ jtp, float* __restrict__ pfT,
    float* __restrict__ Gskin, float* __restrict__ out_Jt) {
  const int parent[24] = {-1, 0, 0, 0, 1, 2, 3, 4, 5, 6, 7, 8,
                          9, 9, 9, 12, 13, 14, 16, 17, 18, 19, 20, 21};
  const int depth[24] = {0, 1, 1, 1, 2, 2, 2, 3, 3, 3, 4, 4,
                         4, 4, 4, 5, 5, 5, 6, 6, 7, 7, 8, 8};
  const int bi = threadIdx.x >> 6;   // batch slot 0..3
  const int j = threadIdx.x & 63;
  const int b = blockIdx.x * 4 + bi;
  __shared__ float G[4][24][12];
  __shared__ float Jp_s[4][24][3];
  float R[9];
  if (j < 24) {
    float t0 = pose[b * 72 + 3 * j + 0];
    float t1 = pose[b * 72 + 3 * j + 1];
    float t2 = pose[b * 72 + 3 * j + 2];
    float a0 = t0 + 1e-8f, a1 = t1 + 1e-8f, a2 = t2 + 1e-8f;
    float angle = sqrtf(a0 * a0 + a1 * a1 + a2 * a2);
    float inv = 1.0f / angle;
    float h = 0.5f * angle;
    float c = cosf(h), s = sinf(h);
    float x = s * t0 * inv, y = s * t1 * inv, z = s * t2 * inv, w = c;
    if (j >= 1) {
      int f = 4 * (j - 1);
      pfT[(size_t)(f + 0) * kB + b] = x;
      pfT[(size_t)(f + 1) * kB + b] = y;
      pfT[(size_t)(f + 2) * kB + b] = z;
      pfT[(size_t)(f + 3) * kB + b] = c - 1.0f;
    } else {
      pfT[(size_t)92 * kB + b] = betas[b * kNB + 1];
    }
    float xx = x * x, yy = y * y, zz = z * z;
    float wx = w * x, wy = w * y, wz = w * z;
    float xy = x * y, xz = x * z, yz = y * z;
    R[0] = 1.f - 2.f * (yy + zz); R[1] = 2.f * (xy - wz); R[2] = 2.f * (xz + wy);
    R[3] = 2.f * (xy + wz); R[4] = 1.f - 2.f * (xx + zz); R[5] = 2.f * (yz - wx);
    R[6] = 2.f * (xz - wy); R[7] = 2.f * (yz + wx); R[8] = 1.f - 2.f * (xx + yy);
    float bet[kNB];
#pragma unroll
    for (int nb = 0; nb < kNB; ++nb) bet[nb] = betas[b * kNB + nb];
#pragma unroll
    for (int k = 0; k < 3; ++k) {
      int jk = j * 3 + k;
      float a = jtp[jk] + jtp[72 + jk] + jtp[144 + jk] + jtp[216 + jk];
#pragma unroll
      for (int nb = 0; nb < kNB; ++nb) {
        float s4 = jsp[jk * kNB + nb] + jsp[720 + jk * kNB + nb] +
                   jsp[1440 + jk * kNB + nb] + jsp[2160 + jk * kNB + nb];
        a += s4 * bet[nb];
      }
      Jp_s[bi][j][k] = a;
    }
  }
  __syncthreads();
  float tl[3];
  if (j < 24) {
    int p = parent[j];
#pragma unroll
    for (int k = 0; k < 3; ++k)
      tl[k] = (p >= 0) ? (Jp_s[bi][j][k] - Jp_s[bi][p][k]) : Jp_s[bi][j][k];
    if (j == 0) {
#pragma unroll
      for (int r = 0; r < 3; ++r) {
        G[bi][0][r * 4 + 0] = R[r * 3 + 0];
        G[bi][0][r * 4 + 1] = R[r * 3 + 1];
        G[bi][0][r * 4 + 2] = R[r * 3 + 2];
        G[bi][0][r * 4 + 3] = tl[r];
      }
    }
  }
  __syncthreads();
  for (int lev = 1; lev <= 8; ++lev) {
    if (j < 24 && depth[j] == lev) {
      int p = parent[j];
      float nG[12];
#pragma unroll
      for (int r = 0; r < 3; ++r) {
        float g0 = G[bi][p][r * 4 + 0], g1 = G[bi][p][r * 4 + 1];
        float g2 = G[bi][p][r * 4 + 2], g3 = G[bi][p][r * 4 + 3];
        nG[r * 4 + 0] = g0 * R[0] + g1 * R[3] + g2 * R[6];
        nG[r * 4 + 1] = g0 * R[1] + g1 * R[4] + g2 * R[7];
        nG[r * 4 + 2] = g0 * R[2] + g1 * R[5] + g2 * R[8];
        nG[r * 4 + 3] = g0 * tl[0] + g1 * tl[1] + g2 * tl[2] + g3;
      }
#pragma unroll
      for (int e = 0; e < 12; ++e) G[bi][j][e] = nG[e];
    }
    __syncthreads();
  }
  if (j < 24) {
    float tr[3];
#pragma unroll
    for (int k = 0; k < 3; ++k) tr[k] = trans[b * 3 + k];
#pragma unroll
    for (int k = 0; k < 3; ++k)
      out_Jt[b * 72 + j * 3 + k] = G[bi][j][k * 4 + 3] + tr[k];
    float jp0 = Jp_s[bi][j][0], jp1 = Jp_s[bi][j][1], jp2 = Jp_s[bi][j][2];
    float* gs = Gskin + b * 288 + j * 12;
#pragma unroll
    for (int r = 0; r < 3; ++r) {
      float t = G[bi][j][r * 4 + 0] * jp0 + G[bi][j][r * 4 + 1] * jp1 +
                G[bi][j][r * 4 + 2] * jp2;
      gs[r * 4 + 0] = G[bi][j][r * 4 + 0];
      gs[r * 4 + 1] = G[bi][j][r * 4 + 1];
      gs[r * 4 + 2] = G[bi][j][r * 4 + 2];
      gs[r * 4 + 3] = G[bi][j][r * 4 + 3] - t;
    }
  }
}

// ---------------------------------------------------------------------------
// K14: r0-proven form, DIAGNOSTIC x3 repetition (idempotent).
// ---------------------------------------------------------------------------
__global__ __launch_bounds__(256) void k14_fused(
    const float* __restrict__ shapedirs, const float* __restrict__ posedirs,
    const float* __restrict__ v_template, const float* __restrict__ betas,
    const float* __restrict__ pfT, float* __restrict__ out_vshaped,
    float* __restrict__ out_vposed) {
  int tid = threadIdx.x;
  int d = blockIdx.x * 256 + tid;
  bool active = d < kD;
  int dl = active ? d : (kD - 1);  // clamp for loads
  int b0 = blockIdx.y * 32;
#pragma unroll 1
  for (int rep = 0; rep < K14_REPS; ++rep) {
    asm volatile("" ::: "memory");  // prevent rep-CSE; forces re-execution
    float sd[kNB], pd[kNF];
#pragma unroll
    for (int k = 0; k < kNB; ++k) sd[k] = shapedirs[(size_t)dl * kNB + k];
#pragma unroll
    for (int f = 0; f < kNF; ++f) pd[f] = posedirs[(size_t)dl * kNF + f];
    float vt = v_template[dl];
#pragma unroll 1
    for (int bc = 0; bc < 4; ++bc) {
      int bb = b0 + bc * 8;
      float as[8], ap[8];
#pragma unroll
      for (int t = 0; t < 8; ++t) {
        const float* be = betas + (size_t)(bb + t) * kNB;  // wave-uniform
        float a = vt;
#pragma unroll
        for (int k = 0; k < kNB; ++k) a += sd[k] * be[k];
        as[t] = a;
        ap[t] = a;
      }
#pragma unroll
      for (int f = 0; f < kNF; ++f) {
        float pdf = pd[f];
        const float* q = pfT + (size_t)f * kB + bb;  // wave-uniform
#pragma unroll
        for (int t = 0; t < 8; ++t) ap[t] += pdf * q[t];
      }
      if (active) {
#pragma unroll
        for (int t = 0; t < 8; ++t) {
          size_t idx = (size_t)(bb + t) * kD + d;
          out_vshaped[idx] = as[t];
          out_vposed[idx] = ap[t];
        }
      }
    }
  }
}

// ---------------------------------------------------------------------------
// K5 v3: r7-proven form, DIAGNOSTIC x5 repetition (idempotent).
// ---------------------------------------------------------------------------
__global__ __launch_bounds__(256) void k5_skin(
    const float* __restrict__ weights, const float* __restrict__ Gskin,
    const float* __restrict__ trans, const float* __restrict__ vposed,
    float* __restrict__ out_v) {
  __shared__ __align__(16) float Gs[8 * 288];  // 9216 B
  int tid = threadIdx.x;
  int v = blockIdx.x * 256 + tid;
  bool active = v < kV;
  int vl = active ? v : (kV - 1);
  int b0 = blockIdx.y * 8;
#pragma unroll 1
  for (int rep = 0; rep < K5_REPS; ++rep) {
    asm volatile("" ::: "memory");  // prevent rep-CSE
    float w[kJ];
#pragma unroll
    for (int j = 0; j < kJ; ++j) w[j] = weights[(size_t)vl * kJ + j];
    {
      const float* src = Gskin + (size_t)b0 * 288;
#pragma unroll
      for (int i = 0; i < 9; ++i) Gs[i * 256 + tid] = src[i * 256 + tid];
    }
    __syncthreads();
#pragma unroll 1
    for (int bi = 0; bi < 8; ++bi) {
      int b = b0 + bi;
      size_t base = (size_t)b * kD + (size_t)vl * 3;
      float q0 = vposed[base + 0];
      float q1 = vposed[base + 1];
      float q2 = vposed[base + 2];
      float tr0 = trans[b * 3 + 0];
      float tr1 = trans[b * 3 + 1];
      float tr2 = trans[b * 3 + 2];
      const float4* Gt = (const float4*)(Gs + bi * 288);
      float T0 = 0.f, T1 = 0.f, T2 = 0.f, T3 = 0.f;
      float T4 = 0.f, T5 = 0.f, T6 = 0.f, T7 = 0.f;
      float T8 = 0.f, T9 = 0.f, T10 = 0.f, T11 = 0.f;
#pragma unroll 4
      for (int j = 0; j < kJ; ++j) {
        float wj = w[j];
        float4 ga = Gt[j * 3 + 0];  // broadcast ds_read_b128
        float4 gb = Gt[j * 3 + 1];
        float4 gc = Gt[j * 3 + 2];
        T0 += wj * ga.x; T1 += wj * ga.y; T2 += wj * ga.z; T3 += wj * ga.w;
        T4 += wj * gb.x; T5 += wj * gb.y; T6 += wj * gb.z; T7 += wj * gb.w;
        T8 += wj * gc.x; T9 += wj * gc.y; T10 += wj * gc.z; T11 += wj * gc.w;
      }
      if (active) {
        out_v[base + 0] = T0 * q0 + T1 * q1 + T2 * q2 + T3 + tr0;
        out_v[base + 1] = T4 * q0 + T5 * q1 + T6 * q2 + T7 + tr1;
        out_v[base + 2] = T8 * q0 + T9 * q1 + T10 * q2 + T11 + tr2;
      }
    }
    __syncthreads();  // protect Gs re-stage next rep
  }
}

// ---------------------------------------------------------------------------
extern "C" void kernel_launch(void* const* d_in, const int* in_sizes, int n_in,
                              void* d_out, int out_size, void* d_ws,
                              size_t ws_size, hipStream_t stream) {
  const float* pose       = (const float*)d_in[0];
  const float* betas      = (const float*)d_in[1];
  const float* trans      = (const float*)d_in[2];
  const float* v_template = (const float*)d_in[3];
  const float* shapedirs  = (const float*)d_in[4];
  const float* posedirs   = (const float*)d_in[5];
  const float* Jreg       = (const float*)d_in[6];
  const float* weights    = (const float*)d_in[7];

  float* out = (float*)d_out;
  float* out_v       = out;
  float* out_vposed  = out + (size_t)kB * kD;
  float* out_vshaped = out + 2 * (size_t)kB * kD;
  float* out_Jt      = out + 3 * (size_t)kB * kD;

  float* wsf   = (float*)d_ws;
  float* pfT   = wsf;                   // kNF*kB
  float* Gskin = pfT + kNF * kB;        // kB*288
  float* jsp   = Gskin + kB * 288;      // 4*72*10
  float* jtp   = jsp + 4 * 720;         // 4*72

  hipLaunchKernelGGL(kA_js, dim3(72, 4), dim3(256), 0, stream, Jreg, shapedirs,
                     v_template, jsp, jtp);
  hipLaunchKernelGGL(kC_batch, dim3(kB / 4), dim3(256), 0, stream, pose, betas,
                     trans, jsp, jtp, pfT, Gskin, out_Jt);
  hipLaunchKernelGGL(k14_fused, dim3((kD + 255) / 256, 16), dim3(256), 0,
                     stream, shapedirs, posedirs, v_template, betas, pfT,
                     out_vshaped, out_vposed);
  hipLaunchKernelGGL(k5_skin, dim3((kV + 255) / 256, 64), dim3(256), 0, stream,
                     weights, Gskin, trans, out_vposed, out_v);
}